// Round 1
// baseline (2980.181 us; speedup 1.0000x reference)
//
#include <hip/hip_runtime.h>
#include <cstdint>

#define B_    64
#define T_    2700
#define HID_  128
#define PRE_  32
#define VMAX_ 256
#define NG_   16   // batch groups = k_scan grid
#define NB_   4    // batches per group

typedef _Float16 half4_t __attribute__((ext_vector_type(4)));
typedef float    f32x4_t __attribute__((ext_vector_type(4)));

#define MFMA16(A, Bv, C) __builtin_amdgcn_mfma_f32_16x16x16f16((A), (Bv), (C), 0, 0, 0)

__device__ __forceinline__ float fast_sigmoid(float x) {
    float t = __builtin_amdgcn_exp2f(-1.4426950408889634f * x);
    return __builtin_amdgcn_rcpf(1.0f + t);
}
__device__ __forceinline__ float fast_tanh(float x) {
    float t = __builtin_amdgcn_exp2f(2.885390081777927f * x);
    return 1.0f - 2.0f * __builtin_amdgcn_rcpf(t + 1.0f);
}
template<int CTRL>
__device__ __forceinline__ float dpp_add(float x) {
    int t = __builtin_amdgcn_update_dpp(0, __float_as_int(x), CTRL, 0xF, 0xF, true);
    return x + __int_as_float(t);
}
__device__ __forceinline__ void fma4(float4& a, const float4 w, const float4 h) {
    a.x += w.x * h.x; a.y += w.y * h.y; a.z += w.z * h.z; a.w += w.w * h.w;
}
__device__ __forceinline__ float hsum4(const float4 a) {
    return (a.x + a.y) + (a.z + a.w);
}

// pull the (sel)-th accumulator element from source lane (addr>>2)
__device__ __forceinline__ float pick_reg(f32x4_t v, int addr, int sel) {
    float t0 = __int_as_float(__builtin_amdgcn_ds_bpermute(addr, __float_as_int(v[0])));
    float t1 = __int_as_float(__builtin_amdgcn_ds_bpermute(addr, __float_as_int(v[1])));
    float t2 = __int_as_float(__builtin_amdgcn_ds_bpermute(addr, __float_as_int(v[2])));
    float t3 = __int_as_float(__builtin_amdgcn_ds_bpermute(addr, __float_as_int(v[3])));
    float a = (sel & 1) ? t1 : t0;
    float b = (sel & 1) ? t3 : t2;
    return (sel & 2) ? b : a;
}

// ---------------------------------------------------------------------------
// Kernel 1: neighborhood assembly + pre = sigmoid(inp @ W_pre.T + b_pre).
// Output is fp16, packed directly in MFMA B-fragment order:
//   pre16[g][t][ck][hi][c][j]  (halves), k = ck*16 + hi*4 + j, c = batch&3,
// so k_scan lanes load their B-fragment with one 8-byte global load.
// ---------------------------------------------------------------------------
__global__ __launch_bounds__(256) void k_pre(const float* __restrict__ x,
                                             const float* __restrict__ W_pre,
                                             const float* __restrict__ b_pre,
                                             _Float16* __restrict__ pre16) {
    int tid  = blockIdx.x * 256 + threadIdx.x;   // < 64*900*3*32
    int i    = tid & 31;          // k index into PRE
    int rest = tid >> 5;          // (b*900+p)*3 + c
    int c    = rest % 3;
    int r2   = rest / 3;          // b*900 + p
    int p    = r2 % 900;
    int b    = r2 / 900;
    int r    = p / 30;
    int cc   = p - r * 30;
    const float* xb = x + b * 3072 + r * 32 + cc;  // x[b][ch][r][cc] at xb[ch*1024]
    float f0 = xb[0],    f1  = xb[1024], f2  = xb[2048];   // tl
    float f3 = xb[1],    f4  = xb[1025], f5  = xb[2049];   // tc
    float f6 = xb[2],    f7  = xb[1026], f8  = xb[2050];   // tr
    float f9 = xb[32],   f10 = xb[1056], f11 = xb[2080];   // lf
    float ct0 = xb[33],  ct1 = xb[1057];                   // ct[0..1]
    float f12 = (c >= 1) ? ct0 : -1.0f;
    float f13 = (c >= 2) ? ct1 : -1.0f;
    const float* w = W_pre + i * 14;
    float d = b_pre[i];
    d += f0*w[0]  + f1*w[1]  + f2*w[2]  + f3*w[3]  + f4*w[4]  + f5*w[5]  + f6*w[6]
       + f7*w[7]  + f8*w[8]  + f9*w[9]  + f10*w[10] + f11*w[11] + f12*w[12] + f13*w[13];

    int t  = p * 3 + c;           // time index
    int g  = b >> 2;              // batch group
    int cs = b & 3;               // batch slot within group
    int k  = i;
    size_t base = ((size_t)g * T_ + t) * 128;     // 128 halves per (g,t)
    int idx = ((k >> 4) << 6) | (((k >> 2) & 3) << 4) | (cs << 2) | (k & 3);
    pre16[base + idx] = (_Float16)fast_sigmoid(d);
}

// ---------------------------------------------------------------------------
// Kernel 2: persistent GRU scan, MFMA version. 16 blocks x 512 threads; each
// block carries 4 batch chains. Wave w owns output rows [16w,16w+16) for all
// gates: r,z fused over K=160 (h||pre), xn over pre, hn over h -> 30
// v_mfma_f32_16x16x16_f16 per wave per step, weights resident in VGPRs
// (30 frags = 60 VGPR). h is exchanged through a 2KB LDS tile stored in
// B-fragment layout (1 b16 write, 8 broadcast b64 reads per lane). Gate sums
// are redistributed with ds_bpermute so each lane runs the nonlinearity for
// exactly ONE (u,batch) element (6 transcendentals/wave/step, no redundancy).
// ONE __syncthreads per step; all global ops issue at the top of the step so
// the barrier's vmcnt drain is hidden.
// ---------------------------------------------------------------------------
__global__ __launch_bounds__(512) void k_scan(const float* __restrict__ W_ih,
                                              const float* __restrict__ b_ih,
                                              const float* __restrict__ W_hh,
                                              const float* __restrict__ b_hh,
                                              const _Float16* __restrict__ pre16,
                                              float* __restrict__ hs) {
    // h state in B-frag layout: [buf][ck][hi][c][j], u = ck*16 + hi*4 + j
    __shared__ __align__(16) _Float16 hbuf[2][8][4][4][4];   // 2 KB

    const int tid  = threadIdx.x;
    const int g    = blockIdx.x;
    const int w    = tid >> 6;          // wave id = u-tile
    const int lane = tid & 63;
    const int lo   = lane & 15;
    const int hi   = lane >> 4;
    const int c4   = lane & 3;
    const int row  = w * 16 + lo;       // this lane's A-operand row (local gate row)

    // ---- weight A-fragments (one-time gather) ----
    half4_t Ar[10], Az[10], Ahn[8], Axn[2];
#pragma unroll
    for (int kc = 0; kc < 8; ++kc) {
        half4_t ar, az, an;
#pragma unroll
        for (int j = 0; j < 4; ++j) {
            int k = kc * 16 + hi * 4 + j;
            ar[j] = (_Float16)W_hh[row * HID_ + k];
            az[j] = (_Float16)W_hh[(128 + row) * HID_ + k];
            an[j] = (_Float16)W_hh[(256 + row) * HID_ + k];
        }
        Ar[kc] = ar; Az[kc] = az; Ahn[kc] = an;
    }
#pragma unroll
    for (int kc = 0; kc < 2; ++kc) {
        half4_t ar, az, ax;
#pragma unroll
        for (int j = 0; j < 4; ++j) {
            int k = kc * 16 + hi * 4 + j;
            ar[j] = (_Float16)W_ih[row * PRE_ + k];
            az[j] = (_Float16)W_ih[(128 + row) * PRE_ + k];
            ax[j] = (_Float16)W_ih[(256 + row) * PRE_ + k];
        }
        Ar[8 + kc] = ar; Az[8 + kc] = az; Axn[kc] = ax;
    }

    // ---- phase-3 element owned by this lane: (u3, batch slot c4) ----
    const int u3 = w * 16 + (lane >> 2);
    const float br  = b_ih[u3]       + b_hh[u3];
    const float bz  = b_ih[128 + u3] + b_hh[128 + u3];
    const float bxn = b_ih[256 + u3];
    const float bhn = b_hh[256 + u3];
    // source lane holding D[row=u3&15][col=c4]: (hi_src = lane>>4, lo_src = c4)
    const int srcaddr = ((((lane >> 4) << 4) | c4) << 2);
    const int sel     = (lane >> 2) & 3;   // accumulator reg index = row & 3

    const char* preg = (const char*)pre16 + (size_t)g * T_ * 256;
    float* hsb = hs + (size_t)(g * NB_ + c4) * T_ * HID_ + u3;

    // zero-init whole hbuf (exactly 512 dwords)
    ((uint32_t*)hbuf)[tid] = 0u;

    half4_t pf0 = *(const half4_t*)(preg + 0   + hi * 32 + c4 * 8);
    half4_t pf1 = *(const half4_t*)(preg + 128 + hi * 32 + c4 * 8);
    float hprev = 0.0f;
    __syncthreads();

    for (int t = 0; t < T_; ++t) {
        // global ops first (drained essentially for free at the end barrier)
        if (t) hsb[(size_t)(t - 1) * HID_] = hprev;
        const int tn = (t + 1 < T_) ? (t + 1) : t;
        half4_t pf0n = *(const half4_t*)(preg + (size_t)tn * 256 +       hi * 32 + c4 * 8);
        half4_t pf1n = *(const half4_t*)(preg + (size_t)tn * 256 + 128 + hi * 32 + c4 * 8);

        const int rb = t & 1;
        half4_t hB[8];
#pragma unroll
        for (int kc = 0; kc < 8; ++kc)
            hB[kc] = *(const half4_t*)&hbuf[rb][kc][hi][lo & 3][0];   // 4-way broadcast

        const f32x4_t Z4 = {0.f, 0.f, 0.f, 0.f};
        f32x4_t r0 = Z4, r1 = Z4, z0 = Z4, z1 = Z4, n0 = Z4, n1 = Z4, xs = Z4;
#pragma unroll
        for (int kc = 0; kc < 4; ++kc) {
            r0 = MFMA16(Ar[kc],  hB[kc], r0);
            z0 = MFMA16(Az[kc],  hB[kc], z0);
            n0 = MFMA16(Ahn[kc], hB[kc], n0);
        }
#pragma unroll
        for (int kc = 4; kc < 8; ++kc) {
            r1 = MFMA16(Ar[kc],  hB[kc], r1);
            z1 = MFMA16(Az[kc],  hB[kc], z1);
            n1 = MFMA16(Ahn[kc], hB[kc], n1);
        }
        r0 = MFMA16(Ar[8], pf0, r0);  r1 = MFMA16(Ar[9], pf1, r1);
        z0 = MFMA16(Az[8], pf0, z0);  z1 = MFMA16(Az[9], pf1, z1);
        xs = MFMA16(Axn[0], pf0, xs); xs = MFMA16(Axn[1], pf1, xs);

        f32x4_t rs = r0 + r1;
        f32x4_t zs = z0 + z1;
        f32x4_t ns = n0 + n1;

        // redistribute: one element per lane
        float srr = pick_reg(rs, srcaddr, sel) + br;
        float szz = pick_reg(zs, srcaddr, sel) + bz;
        float sxn = pick_reg(xs, srcaddr, sel) + bxn;
        float shn = pick_reg(ns, srcaddr, sel) + bhn;

        float rg   = fast_sigmoid(srr);
        float zg   = fast_sigmoid(szz);
        float ng   = fast_tanh(sxn + rg * shn);
        float hnew = ng + zg * (hprev - ng);
        hprev = hnew;

        // write h(t+1 input) in B-frag layout: u3 -> [w][lane>>4][c4][(lane>>2)&3]
        hbuf[rb ^ 1][w][lane >> 4][c4][(lane >> 2) & 3] = (_Float16)hnew;

        pf0 = pf0n; pf1 = pf1n;
        __syncthreads();
    }
    hsb[(size_t)(T_ - 1) * HID_] = hprev;
}

// ---------------------------------------------------------------------------
// Kernel 3: out = hs @ W_post.T + b_post into padded NCHWV layout (unchanged).
// ---------------------------------------------------------------------------
__global__ __launch_bounds__(512, 4) void k_post(const float* __restrict__ W_post,
                                                 const float* __restrict__ b_post,
                                                 const float* __restrict__ hs,
                                                 float* __restrict__ out) {
    __shared__ __align__(16) float sh[2][HID_];
    const int tid  = threadIdx.x;
    const int v    = tid >> 1;
    const int hf   = tid & 1;
    const int blk  = blockIdx.x;       // 64*3*32
    const int i    = blk & 31;
    const int rest = blk >> 5;
    const int ch   = rest % 3;
    const int b    = rest / 3;
    float* outb = out + ((size_t)(b * 3 + ch) * 1024 + i * 32) * VMAX_;

    if (i == 0 || i == 31) {
        if (hf == 0) {
#pragma unroll
            for (int jc = 0; jc < 32; ++jc) outb[jc * VMAX_ + v] = 0.0f;
        }
        return;
    }

    float4 wp[16];
    const float4* wpp = (const float4*)(W_post + (size_t)v * HID_ + hf * 64);
#pragma unroll
    for (int k = 0; k < 16; ++k) wp[k] = wpp[k];
    const float bp = b_post[v];

    const float* hsb = hs + (size_t)b * T_ * HID_;
    const int trow = (i - 1) * 30;     // t = (trow + (jc-1))*3 + ch

    if (tid < 32)
        ((float4*)sh[1])[tid] = ((const float4*)(hsb + (size_t)(trow * 3 + ch) * HID_))[tid];
    if (hf == 0) { outb[v] = 0.0f; outb[31 * VMAX_ + v] = 0.0f; }
    __syncthreads();

    for (int jc = 1; jc <= 30; ++jc) {
        if (tid < 32 && jc < 30)
            ((float4*)sh[(jc + 1) & 1])[tid] =
                ((const float4*)(hsb + (size_t)((trow + jc) * 3 + ch) * HID_))[tid];
        const float4* h4 = (const float4*)sh[jc & 1] + hf * 16;
        float4 a0 = {0,0,0,0}, a1 = {0,0,0,0}, a2 = {0,0,0,0}, a3 = {0,0,0,0};
#pragma unroll
        for (int k = 0; k < 16; k += 4) {
            fma4(a0, wp[k],     h4[k]);
            fma4(a1, wp[k + 1], h4[k + 1]);
            fma4(a2, wp[k + 2], h4[k + 2]);
            fma4(a3, wp[k + 3], h4[k + 3]);
        }
        float s = (hsum4(a0) + hsum4(a1)) + (hsum4(a2) + hsum4(a3));
        s = dpp_add<0xB1>(s);
        if (hf == 0) outb[jc * VMAX_ + v] = bp + s;
        __syncthreads();
    }
}

extern "C" void kernel_launch(void* const* d_in, const int* in_sizes, int n_in,
                              void* d_out, int out_size, void* d_ws, size_t ws_size,
                              hipStream_t stream) {
    const float* x      = (const float*)d_in[0];
    const float* W_pre  = (const float*)d_in[1];
    const float* b_pre  = (const float*)d_in[2];
    const float* W_ih   = (const float*)d_in[3];
    const float* b_ih   = (const float*)d_in[4];
    const float* W_hh   = (const float*)d_in[5];
    const float* b_hh   = (const float*)d_in[6];
    const float* W_post = (const float*)d_in[7];
    const float* b_post = (const float*)d_in[8];
    float* out = (float*)d_out;

    // ws layout: pre16 (16 groups * 2700 * 256 B = 11.06 MB) | hs (64*2700*128 f32 = 88.5 MB)
    _Float16* pre16 = (_Float16*)d_ws;
    float* hs = (float*)((char*)d_ws + (size_t)NG_ * T_ * 256);

    k_pre <<<21600, 256, 0, stream>>>(x, W_pre, b_pre, pre16);
    k_scan<<<NG_,   512, 0, stream>>>(W_ih, b_ih, W_hh, b_hh, pre16, hs);
    k_post<<<6144,  512, 0, stream>>>(W_post, b_post, hs, out);
}

// Round 2
// 2561.597 us; speedup vs baseline: 1.1634x; 1.1634x over previous
//
#include <hip/hip_runtime.h>
#include <cstdint>

#define B_    64
#define T_    2700
#define HID_  128
#define PRE_  32
#define VMAX_ 256
#define NG_   16   // batch groups = k_scan grid
#define NB_   4    // batches per group

typedef _Float16 half8_t __attribute__((ext_vector_type(8)));
typedef float    f32x4_t __attribute__((ext_vector_type(4)));

#define MFMA32(A, Bv, C) __builtin_amdgcn_mfma_f32_16x16x32_f16((A), (Bv), (C), 0, 0, 0)

__device__ __forceinline__ float fast_sigmoid(float x) {
    float t = __builtin_amdgcn_exp2f(-1.4426950408889634f * x);
    return __builtin_amdgcn_rcpf(1.0f + t);
}
__device__ __forceinline__ float fast_tanh(float x) {
    float t = __builtin_amdgcn_exp2f(2.885390081777927f * x);
    return 1.0f - 2.0f * __builtin_amdgcn_rcpf(t + 1.0f);
}
template<int CTRL>
__device__ __forceinline__ float dpp_add(float x) {
    int t = __builtin_amdgcn_update_dpp(0, __float_as_int(x), CTRL, 0xF, 0xF, true);
    return x + __int_as_float(t);
}
__device__ __forceinline__ void fma4(float4& a, const float4 w, const float4 h) {
    a.x += w.x * h.x; a.y += w.y * h.y; a.z += w.z * h.z; a.w += w.w * h.w;
}
__device__ __forceinline__ float hsum4(const float4 a) {
    return (a.x + a.y) + (a.z + a.w);
}

// pull the (sel)-th accumulator element from source lane (addr>>2)
__device__ __forceinline__ float pick_reg(f32x4_t v, int addr, int sel) {
    float t0 = __int_as_float(__builtin_amdgcn_ds_bpermute(addr, __float_as_int(v[0])));
    float t1 = __int_as_float(__builtin_amdgcn_ds_bpermute(addr, __float_as_int(v[1])));
    float t2 = __int_as_float(__builtin_amdgcn_ds_bpermute(addr, __float_as_int(v[2])));
    float t3 = __int_as_float(__builtin_amdgcn_ds_bpermute(addr, __float_as_int(v[3])));
    float a = (sel & 1) ? t1 : t0;
    float b = (sel & 1) ? t3 : t2;
    return (sel & 2) ? b : a;
}

// ---------------------------------------------------------------------------
// Kernel 1: neighborhood assembly + pre = sigmoid(inp @ W_pre.T + b_pre).
// fp16 output packed in the k_scan B-fragment slot convention for the
// 16x16x32 MFMA: slot(hi, j) of lane group hi holds k = hi*8 + j, batch slot
// cs at 16B granularity:  pre16[g][t][hi(4)][cs(4)][j(8)] halves, so a k_scan
// lane reads its full K=32 B-fragment with ONE 16-byte load.
// ---------------------------------------------------------------------------
__global__ __launch_bounds__(256) void k_pre(const float* __restrict__ x,
                                             const float* __restrict__ W_pre,
                                             const float* __restrict__ b_pre,
                                             _Float16* __restrict__ pre16) {
    int tid  = blockIdx.x * 256 + threadIdx.x;   // < 64*900*3*32
    int i    = tid & 31;          // k index into PRE
    int rest = tid >> 5;          // (b*900+p)*3 + c
    int c    = rest % 3;
    int r2   = rest / 3;          // b*900 + p
    int p    = r2 % 900;
    int b    = r2 / 900;
    int r    = p / 30;
    int cc   = p - r * 30;
    const float* xb = x + b * 3072 + r * 32 + cc;  // x[b][ch][r][cc] at xb[ch*1024]
    float f0 = xb[0],    f1  = xb[1024], f2  = xb[2048];   // tl
    float f3 = xb[1],    f4  = xb[1025], f5  = xb[2049];   // tc
    float f6 = xb[2],    f7  = xb[1026], f8  = xb[2050];   // tr
    float f9 = xb[32],   f10 = xb[1056], f11 = xb[2080];   // lf
    float ct0 = xb[33],  ct1 = xb[1057];                   // ct[0..1]
    float f12 = (c >= 1) ? ct0 : -1.0f;
    float f13 = (c >= 2) ? ct1 : -1.0f;
    const float* w = W_pre + i * 14;
    float d = b_pre[i];
    d += f0*w[0]  + f1*w[1]  + f2*w[2]  + f3*w[3]  + f4*w[4]  + f5*w[5]  + f6*w[6]
       + f7*w[7]  + f8*w[8]  + f9*w[9]  + f10*w[10] + f11*w[11] + f12*w[12] + f13*w[13];

    int t  = p * 3 + c;           // time index
    int g  = b >> 2;              // batch group
    int cs = b & 3;               // batch slot within group
    size_t base = ((size_t)g * T_ + t) * 128;     // 128 halves per (g,t)
    int idx = ((i >> 3) << 5) | (cs << 3) | (i & 7);   // [hi][cs][j]
    pre16[base + idx] = (_Float16)fast_sigmoid(d);
}

// ---------------------------------------------------------------------------
// Kernel 2: persistent GRU scan, MFMA v2. 16 blocks x 512 threads; each block
// carries 4 batch chains. Wave w owns output rows [16w,16w+16) for all gates.
// Matvec on v_mfma_f32_16x16x32_f16 (~5cy vs ~16cy for the legacy K=16 op
// that made round-1 slow): r,z fused over K=160 (h||pre) = 5 MFMA each,
// hn = 4, xn = 1 -> 15 MFMA/wave/step, single 5-deep accumulator chains.
// k-slot convention k = 32*kc + 8*hi + j applied identically to A (weights,
// packed at init) and B (h in LDS / pre16) -> correct for any symmetric HW
// k-map (same argument that validated round-1's 16x16x16 packing).
// h exchange: 2KB LDS tile, 4x ds_read_b128 (4-way broadcast, conflict-free),
// 1 ds_write_b16 per lane. Gate sums redistributed with ds_bpermute so each
// lane runs the nonlinearity for exactly ONE (u,batch) element. ONE
// __syncthreads per step.
// ---------------------------------------------------------------------------
__global__ __launch_bounds__(512) void k_scan(const float* __restrict__ W_ih,
                                              const float* __restrict__ b_ih,
                                              const float* __restrict__ W_hh,
                                              const float* __restrict__ b_hh,
                                              const _Float16* __restrict__ pre16,
                                              float* __restrict__ hs) {
    // h state in B-frag layout: [buf][kc][hi][c][j], u = kc*32 + hi*8 + j
    __shared__ __align__(16) _Float16 hbuf[2][4][4][4][8];   // 2 KB

    const int tid  = threadIdx.x;
    const int g    = blockIdx.x;
    const int w    = tid >> 6;          // wave id = u-tile
    const int lane = tid & 63;
    const int lo   = lane & 15;
    const int hi   = lane >> 4;
    const int c4   = lane & 3;
    const int row  = w * 16 + lo;       // this lane's A-operand row (local gate row)

    // ---- weight A-fragments (one-time gather), slot j -> k = 32*kc + 8*hi + j
    half8_t Ar[5], Az[5], Ahn[4], Axn;
#pragma unroll
    for (int kc = 0; kc < 4; ++kc) {
        half8_t ar, az, an;
#pragma unroll
        for (int j = 0; j < 8; ++j) {
            int k = kc * 32 + hi * 8 + j;
            ar[j] = (_Float16)W_hh[row * HID_ + k];
            az[j] = (_Float16)W_hh[(128 + row) * HID_ + k];
            an[j] = (_Float16)W_hh[(256 + row) * HID_ + k];
        }
        Ar[kc] = ar; Az[kc] = az; Ahn[kc] = an;
    }
    {
        half8_t ar, az, ax;
#pragma unroll
        for (int j = 0; j < 8; ++j) {
            int k = hi * 8 + j;
            ar[j] = (_Float16)W_ih[row * PRE_ + k];
            az[j] = (_Float16)W_ih[(128 + row) * PRE_ + k];
            ax[j] = (_Float16)W_ih[(256 + row) * PRE_ + k];
        }
        Ar[4] = ar; Az[4] = az; Axn = ax;
    }

    // ---- phase-3 element owned by this lane: (u3, batch slot c4) ----
    const int u3 = w * 16 + (lane >> 2);
    const float br  = b_ih[u3]       + b_hh[u3];
    const float bz  = b_ih[128 + u3] + b_hh[128 + u3];
    const float bxn = b_ih[256 + u3];
    const float bhn = b_hh[256 + u3];
    // source lane holding D[row=u3&15][col=c4]
    const int srcaddr = ((((lane >> 4) << 4) | c4) << 2);
    const int sel     = (lane >> 2) & 3;   // accumulator reg index = row & 3

    const char* preg  = (const char*)pre16 + (size_t)g * T_ * 256;
    const int   pfoff = hi * 64 + c4 * 16;
    float* hsb = hs + (size_t)(g * NB_ + c4) * T_ * HID_ + u3;

    // h write slot for (u3, c4): kc = u3>>5, hi_w = (u3&31)>>3, j_w = u3&7
    const int kc_w = u3 >> 5;
    const int hi_w = (u3 >> 3) & 3;
    const int j_w  = u3 & 7;

    // zero-init whole hbuf (exactly 512 dwords)
    ((uint32_t*)hbuf)[tid] = 0u;

    half8_t pf = *(const half8_t*)(preg + pfoff);
    float hprev = 0.0f;
    __syncthreads();

    for (int t = 0; t < T_; ++t) {
        const int tn = (t + 1 < T_) ? (t + 1) : t;
        half8_t pfn = *(const half8_t*)(preg + (size_t)tn * 256 + pfoff);

        const int rb = t & 1;
        half8_t hB[4];
#pragma unroll
        for (int kc = 0; kc < 4; ++kc)
            hB[kc] = *(const half8_t*)&hbuf[rb][kc][hi][c4][0];   // 4-way broadcast b128

        const f32x4_t Z4 = {0.f, 0.f, 0.f, 0.f};
        f32x4_t r = Z4, z = Z4, n = Z4, xs = Z4;
        r = MFMA32(Ar[0], hB[0], r);
        z = MFMA32(Az[0], hB[0], z);
        n = MFMA32(Ahn[0], hB[0], n);
        xs = MFMA32(Axn, pf, xs);
        r = MFMA32(Ar[1], hB[1], r);
        z = MFMA32(Az[1], hB[1], z);
        n = MFMA32(Ahn[1], hB[1], n);
        r = MFMA32(Ar[2], hB[2], r);
        z = MFMA32(Az[2], hB[2], z);
        n = MFMA32(Ahn[2], hB[2], n);
        r = MFMA32(Ar[3], hB[3], r);
        z = MFMA32(Az[3], hB[3], z);
        n = MFMA32(Ahn[3], hB[3], n);
        r = MFMA32(Ar[4], pf, r);
        z = MFMA32(Az[4], pf, z);

        // redistribute: one element per lane
        float srr = pick_reg(r,  srcaddr, sel) + br;
        float szz = pick_reg(z,  srcaddr, sel) + bz;
        float sxn = pick_reg(xs, srcaddr, sel) + bxn;
        float shn = pick_reg(n,  srcaddr, sel) + bhn;

        float rg   = fast_sigmoid(srr);
        float zg   = fast_sigmoid(szz);
        float ng   = fast_tanh(sxn + rg * shn);
        float hnew = ng + zg * (hprev - ng);
        hprev = hnew;

        // write h(t+1 input) in B-frag layout
        hbuf[rb ^ 1][kc_w][hi_w][c4][j_w] = (_Float16)hnew;
        hsb[(size_t)t * HID_] = hnew;

        pf = pfn;
        __syncthreads();
    }
}

// ---------------------------------------------------------------------------
// Kernel 3: out = hs @ W_post.T + b_post into padded NCHWV layout (unchanged).
// ---------------------------------------------------------------------------
__global__ __launch_bounds__(512, 4) void k_post(const float* __restrict__ W_post,
                                                 const float* __restrict__ b_post,
                                                 const float* __restrict__ hs,
                                                 float* __restrict__ out) {
    __shared__ __align__(16) float sh[2][HID_];
    const int tid  = threadIdx.x;
    const int v    = tid >> 1;
    const int hf   = tid & 1;
    const int blk  = blockIdx.x;       // 64*3*32
    const int i    = blk & 31;
    const int rest = blk >> 5;
    const int ch   = rest % 3;
    const int b    = rest / 3;
    float* outb = out + ((size_t)(b * 3 + ch) * 1024 + i * 32) * VMAX_;

    if (i == 0 || i == 31) {
        if (hf == 0) {
#pragma unroll
            for (int jc = 0; jc < 32; ++jc) outb[jc * VMAX_ + v] = 0.0f;
        }
        return;
    }

    float4 wp[16];
    const float4* wpp = (const float4*)(W_post + (size_t)v * HID_ + hf * 64);
#pragma unroll
    for (int k = 0; k < 16; ++k) wp[k] = wpp[k];
    const float bp = b_post[v];

    const float* hsb = hs + (size_t)b * T_ * HID_;
    const int trow = (i - 1) * 30;     // t = (trow + (jc-1))*3 + ch

    if (tid < 32)
        ((float4*)sh[1])[tid] = ((const float4*)(hsb + (size_t)(trow * 3 + ch) * HID_))[tid];
    if (hf == 0) { outb[v] = 0.0f; outb[31 * VMAX_ + v] = 0.0f; }
    __syncthreads();

    for (int jc = 1; jc <= 30; ++jc) {
        if (tid < 32 && jc < 30)
            ((float4*)sh[(jc + 1) & 1])[tid] =
                ((const float4*)(hsb + (size_t)((trow + jc) * 3 + ch) * HID_))[tid];
        const float4* h4 = (const float4*)sh[jc & 1] + hf * 16;
        float4 a0 = {0,0,0,0}, a1 = {0,0,0,0}, a2 = {0,0,0,0}, a3 = {0,0,0,0};
#pragma unroll
        for (int k = 0; k < 16; k += 4) {
            fma4(a0, wp[k],     h4[k]);
            fma4(a1, wp[k + 1], h4[k + 1]);
            fma4(a2, wp[k + 2], h4[k + 2]);
            fma4(a3, wp[k + 3], h4[k + 3]);
        }
        float s = (hsum4(a0) + hsum4(a1)) + (hsum4(a2) + hsum4(a3));
        s = dpp_add<0xB1>(s);
        if (hf == 0) outb[jc * VMAX_ + v] = bp + s;
        __syncthreads();
    }
}

extern "C" void kernel_launch(void* const* d_in, const int* in_sizes, int n_in,
                              void* d_out, int out_size, void* d_ws, size_t ws_size,
                              hipStream_t stream) {
    const float* x      = (const float*)d_in[0];
    const float* W_pre  = (const float*)d_in[1];
    const float* b_pre  = (const float*)d_in[2];
    const float* W_ih   = (const float*)d_in[3];
    const float* b_ih   = (const float*)d_in[4];
    const float* W_hh   = (const float*)d_in[5];
    const float* b_hh   = (const float*)d_in[6];
    const float* W_post = (const float*)d_in[7];
    const float* b_post = (const float*)d_in[8];
    float* out = (float*)d_out;

    // ws layout: pre16 (16 groups * 2700 * 256 B = 11.06 MB) | hs (64*2700*128 f32 = 88.5 MB)
    _Float16* pre16 = (_Float16*)d_ws;
    float* hs = (float*)((char*)d_ws + (size_t)NG_ * T_ * 256);

    k_pre <<<21600, 256, 0, stream>>>(x, W_pre, b_pre, pre16);
    k_scan<<<NG_,   512, 0, stream>>>(W_ih, b_ih, W_hh, b_hh, pre16, hs);
    k_post<<<6144,  512, 0, stream>>>(W_post, b_post, hs, out);
}

// Round 3
// 2101.591 us; speedup vs baseline: 1.4181x; 1.2189x over previous
//
#include <hip/hip_runtime.h>
#include <cstdint>

#define B_    64
#define T_    2700
#define HID_  128
#define PRE_  32
#define VMAX_ 256
#define NG_   16   // batch groups = k_scan grid
#define NB_   4    // batches per group
#define TCH_  27   // k_xg t-chunks
#define TSZ_  100  // t per chunk

typedef _Float16 half2_t __attribute__((ext_vector_type(2)));
typedef _Float16 half4_t __attribute__((ext_vector_type(4)));
typedef _Float16 half8_t __attribute__((ext_vector_type(8)));
typedef float    f32x4_t __attribute__((ext_vector_type(4)));
union H8u { half8_t v; half2_t p[4]; };

#define MFMA32(A, Bv, C) __builtin_amdgcn_mfma_f32_16x16x32_f16((A), (Bv), (C), 0, 0, 0)

#if __has_builtin(__builtin_amdgcn_fdot2)
__device__ __forceinline__ float FDOT2(half2_t a, half2_t b, float c) {
    return __builtin_amdgcn_fdot2(a, b, c, false);
}
#else
__device__ __forceinline__ float FDOT2(half2_t a, half2_t b, float c) {
    return c + (float)a[0] * (float)b[0] + (float)a[1] * (float)b[1];
}
#endif

__device__ __forceinline__ half2_t mk2(float a, float b) {
    half2_t r; r[0] = (_Float16)a; r[1] = (_Float16)b; return r;
}
__device__ __forceinline__ float fast_sigmoid(float x) {
    float t = __builtin_amdgcn_exp2f(-1.4426950408889634f * x);
    return __builtin_amdgcn_rcpf(1.0f + t);
}
__device__ __forceinline__ float fast_tanh(float x) {
    float t = __builtin_amdgcn_exp2f(2.885390081777927f * x);
    return 1.0f - 2.0f * __builtin_amdgcn_rcpf(t + 1.0f);
}
template<int CTRL>
__device__ __forceinline__ float dpp_add(float x) {
    int t = __builtin_amdgcn_update_dpp(0, __float_as_int(x), CTRL, 0xF, 0xF, true);
    return x + __int_as_float(t);
}
__device__ __forceinline__ void fma4(float4& a, const float4 w, const float4 h) {
    a.x += w.x * h.x; a.y += w.y * h.y; a.z += w.z * h.z; a.w += w.w * h.w;
}
__device__ __forceinline__ float hsum4(const float4 a) {
    return (a.x + a.y) + (a.z + a.w);
}
// pull the (sel)-th accumulator element from source lane (addr>>2)
__device__ __forceinline__ float pick_reg(f32x4_t v, int addr, int sel) {
    float t0 = __int_as_float(__builtin_amdgcn_ds_bpermute(addr, __float_as_int(v[0])));
    float t1 = __int_as_float(__builtin_amdgcn_ds_bpermute(addr, __float_as_int(v[1])));
    float t2 = __int_as_float(__builtin_amdgcn_ds_bpermute(addr, __float_as_int(v[2])));
    float t3 = __int_as_float(__builtin_amdgcn_ds_bpermute(addr, __float_as_int(v[3])));
    float a = (sel & 1) ? t1 : t0;
    float b = (sel & 1) ? t3 : t2;
    return (sel & 2) ? b : a;
}

// ---------------------------------------------------------------------------
// Kernel 1: neighborhood assembly + pre = sigmoid(inp @ W_pre.T + b_pre).
// fp16 output packed for K=32 B-fragments: pre16[g][t][hi(4)][cs(4)][j(8)].
// ---------------------------------------------------------------------------
__global__ __launch_bounds__(256) void k_pre(const float* __restrict__ x,
                                             const float* __restrict__ W_pre,
                                             const float* __restrict__ b_pre,
                                             _Float16* __restrict__ pre16) {
    int tid  = blockIdx.x * 256 + threadIdx.x;   // < 64*900*3*32
    int i    = tid & 31;          // k index into PRE
    int rest = tid >> 5;          // (b*900+p)*3 + c
    int c    = rest % 3;
    int r2   = rest / 3;          // b*900 + p
    int p    = r2 % 900;
    int b    = r2 / 900;
    int r    = p / 30;
    int cc   = p - r * 30;
    const float* xb = x + b * 3072 + r * 32 + cc;  // x[b][ch][r][cc] at xb[ch*1024]
    float f0 = xb[0],    f1  = xb[1024], f2  = xb[2048];   // tl
    float f3 = xb[1],    f4  = xb[1025], f5  = xb[2049];   // tc
    float f6 = xb[2],    f7  = xb[1026], f8  = xb[2050];   // tr
    float f9 = xb[32],   f10 = xb[1056], f11 = xb[2080];   // lf
    float ct0 = xb[33],  ct1 = xb[1057];                   // ct[0..1]
    float f12 = (c >= 1) ? ct0 : -1.0f;
    float f13 = (c >= 2) ? ct1 : -1.0f;
    const float* w = W_pre + i * 14;
    float d = b_pre[i];
    d += f0*w[0]  + f1*w[1]  + f2*w[2]  + f3*w[3]  + f4*w[4]  + f5*w[5]  + f6*w[6]
       + f7*w[7]  + f8*w[8]  + f9*w[9]  + f10*w[10] + f11*w[11] + f12*w[12] + f13*w[13];

    int t  = p * 3 + c;           // time index
    int g  = b >> 2;              // batch group
    int cs = b & 3;               // batch slot within group
    size_t base = ((size_t)g * T_ + t) * 128;     // 128 halves per (g,t)
    int idx = ((i >> 3) << 5) | (cs << 3) | (i & 7);   // [hi][cs][j]
    pre16[base + idx] = (_Float16)fast_sigmoid(d);
}

// ---------------------------------------------------------------------------
// Kernel 1b: xg precompute — the x-side gate pre-activations (no h dep).
// FULL: xg[g][t][tid] = {xr'=pre.Wr+br+bhr, xz'=..., xn'=pre.Wn+bn, pad} fp16
// (half4, 8B/thread).  !FULL: only the xn' plane (2B/thread).
// Thread tid maps exactly to k_scan's (u3 = (tid>>6)*16 + ((tid&63)>>2),
// c4 = tid&3), so k_scan loads its values with one coalesced load.
// ---------------------------------------------------------------------------
template<bool FULL>
__global__ __launch_bounds__(512) void k_xg(const float* __restrict__ W_ih,
                                            const float* __restrict__ b_ih,
                                            const float* __restrict__ b_hh,
                                            const _Float16* __restrict__ pre16,
                                            _Float16* __restrict__ xg16) {
    const int tid = threadIdx.x;
    const int g   = blockIdx.x / TCH_;
    const int tc  = blockIdx.x % TCH_;
    const int u3  = (tid >> 6) * 16 + ((tid & 63) >> 2);
    const int c4  = tid & 3;

    half2_t wr[16], wz[16], wn[16];
    const float* Wn = W_ih + (size_t)(256 + u3) * PRE_;
#pragma unroll
    for (int k2 = 0; k2 < 16; ++k2) wn[k2] = mk2(Wn[2*k2], Wn[2*k2 + 1]);
    const float bn = b_ih[256 + u3];
    float br = 0.f, bz = 0.f;
    if (FULL) {
        const float* Wr = W_ih + (size_t)u3 * PRE_;
        const float* Wz = W_ih + (size_t)(128 + u3) * PRE_;
#pragma unroll
        for (int k2 = 0; k2 < 16; ++k2) {
            wr[k2] = mk2(Wr[2*k2], Wr[2*k2 + 1]);
            wz[k2] = mk2(Wz[2*k2], Wz[2*k2 + 1]);
        }
        br = b_ih[u3] + b_hh[u3];
        bz = b_ih[128 + u3] + b_hh[128 + u3];
    }

    const char* preg = (const char*)pre16 + ((size_t)g * T_ + (size_t)tc * TSZ_) * 256 + c4 * 16;
    H8u pc0, pc1, pc2, pc3;
    pc0.v = *(const half8_t*)(preg +   0);
    pc1.v = *(const half8_t*)(preg +  64);
    pc2.v = *(const half8_t*)(preg + 128);
    pc3.v = *(const half8_t*)(preg + 192);

    for (int tt = 0; tt < TSZ_; ++tt) {
        const int ttn = (tt + 1 < TSZ_) ? tt + 1 : tt;
        H8u n0, n1, n2, n3;
        n0.v = *(const half8_t*)(preg + (size_t)ttn * 256 +   0);
        n1.v = *(const half8_t*)(preg + (size_t)ttn * 256 +  64);
        n2.v = *(const half8_t*)(preg + (size_t)ttn * 256 + 128);
        n3.v = *(const half8_t*)(preg + (size_t)ttn * 256 + 192);

        float an = bn;
#pragma unroll
        for (int j2 = 0; j2 < 4; ++j2) an = FDOT2(wn[ 0 + j2], pc0.p[j2], an);
#pragma unroll
        for (int j2 = 0; j2 < 4; ++j2) an = FDOT2(wn[ 4 + j2], pc1.p[j2], an);
#pragma unroll
        for (int j2 = 0; j2 < 4; ++j2) an = FDOT2(wn[ 8 + j2], pc2.p[j2], an);
#pragma unroll
        for (int j2 = 0; j2 < 4; ++j2) an = FDOT2(wn[12 + j2], pc3.p[j2], an);

        const size_t t = (size_t)tc * TSZ_ + tt;
        if (FULL) {
            float ar = br, az = bz;
#pragma unroll
            for (int j2 = 0; j2 < 4; ++j2) { ar = FDOT2(wr[ 0 + j2], pc0.p[j2], ar); az = FDOT2(wz[ 0 + j2], pc0.p[j2], az); }
#pragma unroll
            for (int j2 = 0; j2 < 4; ++j2) { ar = FDOT2(wr[ 4 + j2], pc1.p[j2], ar); az = FDOT2(wz[ 4 + j2], pc1.p[j2], az); }
#pragma unroll
            for (int j2 = 0; j2 < 4; ++j2) { ar = FDOT2(wr[ 8 + j2], pc2.p[j2], ar); az = FDOT2(wz[ 8 + j2], pc2.p[j2], az); }
#pragma unroll
            for (int j2 = 0; j2 < 4; ++j2) { ar = FDOT2(wr[12 + j2], pc3.p[j2], ar); az = FDOT2(wz[12 + j2], pc3.p[j2], az); }
            half4_t o;
            o[0] = (_Float16)ar; o[1] = (_Float16)az; o[2] = (_Float16)an; o[3] = (_Float16)0.f;
            *(half4_t*)((char*)xg16 + (((size_t)g * T_ + t) * 512 + tid) * 8) = o;
        } else {
            xg16[((size_t)g * T_ + t) * 512 + tid] = (_Float16)an;
        }
        pc0 = n0; pc1 = n1; pc2 = n2; pc3 = n3;
    }
}

// ---------------------------------------------------------------------------
// Kernel 2: persistent GRU scan v3. 16 blocks x 512 thr, 4 batch chains each.
// FULL: h-only MFMAs (r,z,n over K=128 = 12/wave); x-side read from xg16.
// !FULL: r,z fused over K=160 (14 MFMA/wave) + xn from xg16 plane.
// Raw barrier: s_waitcnt lgkmcnt(0) + s_barrier — global stores / prefetch
// loads stay in flight across the barrier (no per-step vmcnt(0) drain).
// hs stored fp16 (same value as hbuf), halving write traffic.
// ---------------------------------------------------------------------------
template<bool FULL>
__global__ __launch_bounds__(512, 1) void k_scan(const float* __restrict__ W_ih,
                                                 const float* __restrict__ b_ih,
                                                 const float* __restrict__ W_hh,
                                                 const float* __restrict__ b_hh,
                                                 const _Float16* __restrict__ pre16,
                                                 const _Float16* __restrict__ xg16,
                                                 _Float16* __restrict__ hs16) {
    // h state in B-frag layout: [buf][kc][hi][c][j], u = kc*32 + hi*8 + j
    __shared__ __align__(16) _Float16 hbuf[2][4][4][4][8];   // 2 KB

    const int tid  = threadIdx.x;
    const int g    = blockIdx.x;
    const int w    = tid >> 6;          // wave id = u-tile
    const int lane = tid & 63;
    const int lo   = lane & 15;
    const int hi   = lane >> 4;
    const int c4   = lane & 3;
    const int row  = w * 16 + lo;       // this lane's A-operand row

    // ---- weight A-fragments, slot j -> k = 32*kc + 8*hi + j ----
    half8_t Ar[5], Az[5], Ahn[4];
#pragma unroll
    for (int kc = 0; kc < 4; ++kc) {
        half8_t ar, az, an;
#pragma unroll
        for (int j = 0; j < 8; ++j) {
            int k = kc * 32 + hi * 8 + j;
            ar[j] = (_Float16)W_hh[row * HID_ + k];
            az[j] = (_Float16)W_hh[(128 + row) * HID_ + k];
            an[j] = (_Float16)W_hh[(256 + row) * HID_ + k];
        }
        Ar[kc] = ar; Az[kc] = az; Ahn[kc] = an;
    }
    if (!FULL) {
        half8_t ar, az;
#pragma unroll
        for (int j = 0; j < 8; ++j) {
            int k = hi * 8 + j;
            ar[j] = (_Float16)W_ih[row * PRE_ + k];
            az[j] = (_Float16)W_ih[(128 + row) * PRE_ + k];
        }
        Ar[4] = ar; Az[4] = az;
    }

    // ---- phase-3 element owned by this lane: (u3, batch slot c4) ----
    const int u3 = w * 16 + (lane >> 2);
    float br = 0.f, bz = 0.f;
    if (!FULL) { br = b_ih[u3] + b_hh[u3]; bz = b_ih[128 + u3] + b_hh[128 + u3]; }
    const float bhn = b_hh[256 + u3];
    const int srcaddr = ((((lane >> 4) << 4) | c4) << 2);
    const int sel     = (lane >> 2) & 3;

    const char* preg  = (const char*)pre16 + (size_t)g * T_ * 256;
    const int   pfoff = hi * 64 + c4 * 16;
    const char*      xgp = (const char*)xg16 + (((size_t)g * T_) * 512 + tid) * 8;  // FULL
    const _Float16*  xgs = xg16 + (size_t)g * T_ * 512 + tid;                       // !FULL
    _Float16* hsb = hs16 + (size_t)(g * NB_ + c4) * T_ * HID_ + u3;

    const int kc_w = u3 >> 5;
    const int hi_w = (u3 >> 3) & 3;
    const int j_w  = u3 & 7;

    ((uint32_t*)hbuf)[tid] = 0u;   // zero-init (exactly 512 dwords)

    half8_t  pf{};
    half4_t  xh{};
    _Float16 xnf = (_Float16)0.f;
    if (FULL) xh = *(const half4_t*)xgp;
    else { pf = *(const half8_t*)(preg + pfoff); xnf = xgs[0]; }
    float hprev = 0.0f;
    __syncthreads();

    for (int t = 0; t < T_; ++t) {
        const int tn = (t + 1 < T_) ? (t + 1) : t;
        half8_t pfn{}; half4_t xhn{}; _Float16 xnn = (_Float16)0.f;
        if (FULL) {
            xhn = *(const half4_t*)(xgp + (size_t)tn * 4096);
        } else {
            pfn = *(const half8_t*)(preg + (size_t)tn * 256 + pfoff);
            xnn = xgs[(size_t)tn * 512];
        }

        const int rb = t & 1;
        half8_t hB[4];
#pragma unroll
        for (int kc = 0; kc < 4; ++kc)
            hB[kc] = *(const half8_t*)&hbuf[rb][kc][hi][c4][0];   // 4-way broadcast b128

        const f32x4_t Z4 = {0.f, 0.f, 0.f, 0.f};
        f32x4_t r = Z4, z = Z4, n = Z4;
        r = MFMA32(Ar[0],  hB[0], r);
        z = MFMA32(Az[0],  hB[0], z);
        n = MFMA32(Ahn[0], hB[0], n);
        r = MFMA32(Ar[1],  hB[1], r);
        z = MFMA32(Az[1],  hB[1], z);
        n = MFMA32(Ahn[1], hB[1], n);
        r = MFMA32(Ar[2],  hB[2], r);
        z = MFMA32(Az[2],  hB[2], z);
        n = MFMA32(Ahn[2], hB[2], n);
        r = MFMA32(Ar[3],  hB[3], r);
        z = MFMA32(Az[3],  hB[3], z);
        n = MFMA32(Ahn[3], hB[3], n);
        if (!FULL) {
            r = MFMA32(Ar[4], pf, r);
            z = MFMA32(Az[4], pf, z);
        }

        float srr = pick_reg(r, srcaddr, sel);
        float szz = pick_reg(z, srcaddr, sel);
        float shn = pick_reg(n, srcaddr, sel) + bhn;
        float sxn;
        if (FULL) { srr += (float)xh[0]; szz += (float)xh[1]; sxn = (float)xh[2]; }
        else      { srr += br;           szz += bz;           sxn = (float)xnf;  }

        float rg   = fast_sigmoid(srr);
        float zg   = fast_sigmoid(szz);
        float ng   = fast_tanh(sxn + rg * shn);
        float hnew = ng + zg * (hprev - ng);
        hprev = hnew;
        _Float16 h16 = (_Float16)hnew;

        hbuf[rb ^ 1][kc_w][hi_w][c4][j_w] = h16;
        hsb[(size_t)t * HID_] = h16;

        if (FULL) xh = xhn; else { pf = pfn; xnf = xnn; }

        // LDS-only barrier: hbuf write visible; vmem stays in flight.
        asm volatile("s_waitcnt lgkmcnt(0)" ::: "memory");
        __builtin_amdgcn_s_barrier();
    }
}

// ---------------------------------------------------------------------------
// Kernel 3: out = hs @ W_post.T + b_post into padded NCHWV layout.
// hs is now fp16; 32 loader threads convert rows to f32 in LDS.
// ---------------------------------------------------------------------------
__global__ __launch_bounds__(512, 4) void k_post(const float* __restrict__ W_post,
                                                 const float* __restrict__ b_post,
                                                 const _Float16* __restrict__ hs,
                                                 float* __restrict__ out) {
    __shared__ __align__(16) float sh[2][HID_];
    const int tid  = threadIdx.x;
    const int v    = tid >> 1;
    const int hf   = tid & 1;
    const int blk  = blockIdx.x;       // 64*3*32
    const int i    = blk & 31;
    const int rest = blk >> 5;
    const int ch   = rest % 3;
    const int b    = rest / 3;
    float* outb = out + ((size_t)(b * 3 + ch) * 1024 + i * 32) * VMAX_;

    if (i == 0 || i == 31) {
        if (hf == 0) {
#pragma unroll
            for (int jc = 0; jc < 32; ++jc) outb[jc * VMAX_ + v] = 0.0f;
        }
        return;
    }

    float4 wp[16];
    const float4* wpp = (const float4*)(W_post + (size_t)v * HID_ + hf * 64);
#pragma unroll
    for (int k = 0; k < 16; ++k) wp[k] = wpp[k];
    const float bp = b_post[v];

    const _Float16* hsb = hs + (size_t)b * T_ * HID_;
    const int trow = (i - 1) * 30;     // t = (trow + (jc-1))*3 + ch

    if (tid < 32) {
        half4_t hv = ((const half4_t*)(hsb + (size_t)(trow * 3 + ch) * HID_))[tid];
        float4 f = {(float)hv[0], (float)hv[1], (float)hv[2], (float)hv[3]};
        ((float4*)sh[1])[tid] = f;
    }
    if (hf == 0) { outb[v] = 0.0f; outb[31 * VMAX_ + v] = 0.0f; }
    __syncthreads();

    for (int jc = 1; jc <= 30; ++jc) {
        if (tid < 32 && jc < 30) {
            half4_t hv = ((const half4_t*)(hsb + (size_t)((trow + jc) * 3 + ch) * HID_))[tid];
            float4 f = {(float)hv[0], (float)hv[1], (float)hv[2], (float)hv[3]};
            ((float4*)sh[(jc + 1) & 1])[tid] = f;
        }
        const float4* h4 = (const float4*)sh[jc & 1] + hf * 16;
        float4 a0 = {0,0,0,0}, a1 = {0,0,0,0}, a2 = {0,0,0,0}, a3 = {0,0,0,0};
#pragma unroll
        for (int k = 0; k < 16; k += 4) {
            fma4(a0, wp[k],     h4[k]);
            fma4(a1, wp[k + 1], h4[k + 1]);
            fma4(a2, wp[k + 2], h4[k + 2]);
            fma4(a3, wp[k + 3], h4[k + 3]);
        }
        float s = (hsum4(a0) + hsum4(a1)) + (hsum4(a2) + hsum4(a3));
        s = dpp_add<0xB1>(s);
        if (hf == 0) outb[jc * VMAX_ + v] = bp + s;
        __syncthreads();
    }
}

extern "C" void kernel_launch(void* const* d_in, const int* in_sizes, int n_in,
                              void* d_out, int out_size, void* d_ws, size_t ws_size,
                              hipStream_t stream) {
    const float* x      = (const float*)d_in[0];
    const float* W_pre  = (const float*)d_in[1];
    const float* b_pre  = (const float*)d_in[2];
    const float* W_ih   = (const float*)d_in[3];
    const float* b_ih   = (const float*)d_in[4];
    const float* W_hh   = (const float*)d_in[5];
    const float* b_hh   = (const float*)d_in[6];
    const float* W_post = (const float*)d_in[7];
    const float* b_post = (const float*)d_in[8];
    float* out = (float*)d_out;

    const size_t pre_bytes = (size_t)NG_ * T_ * 256;       // 11.06 MB
    const size_t xg_full   = (size_t)NG_ * T_ * 512 * 8;   // 176.9 MB
    const size_t xg_fb     = (size_t)NG_ * T_ * 512 * 2;   // 44.2 MB
    const size_t hs_bytes  = (size_t)B_ * T_ * HID_ * 2;   // 44.2 MB
    const bool full = ws_size >= pre_bytes + xg_full + hs_bytes;

    _Float16* pre16 = (_Float16*)d_ws;
    _Float16* xg    = (_Float16*)((char*)d_ws + pre_bytes);
    _Float16* hs16  = (_Float16*)((char*)d_ws + pre_bytes + (full ? xg_full : xg_fb));

    k_pre<<<21600, 256, 0, stream>>>(x, W_pre, b_pre, pre16);
    if (full) {
        k_xg<true><<<NG_ * TCH_, 512, 0, stream>>>(W_ih, b_ih, b_hh, pre16, xg);
        k_scan<true><<<NG_, 512, 0, stream>>>(W_ih, b_ih, W_hh, b_hh, pre16, xg, hs16);
    } else {
        k_xg<false><<<NG_ * TCH_, 512, 0, stream>>>(W_ih, b_ih, b_hh, pre16, xg);
        k_scan<false><<<NG_, 512, 0, stream>>>(W_ih, b_ih, W_hh, b_hh, pre16, xg, hs16);
    }
    k_post<<<6144, 512, 0, stream>>>(W_post, b_post, hs16, out);
}